// Round 1
// baseline (362.011 us; speedup 1.0000x reference)
//
#include <hip/hip_runtime.h>
#include <math.h>

// One wave (64 lanes) per batch element; lane index == embedding dim d (D=64).
// Block = 256 threads = 4 waves = 4 batch elements.
// All __syncthreads() are reached uniformly by every wave in the block.
__global__ __launch_bounds__(256) void pifsa_gnn_kernel(
    const int*   __restrict__ u,          // [B]
    const int*   __restrict__ v,          // [B]
    const int*   __restrict__ uai,        // [B,8] user_and_item_adj
    const int*   __restrict__ adj_ent,    // [NUM_ENT,8]
    const int*   __restrict__ adj_rel,    // [NUM_ENT,8]
    const float* __restrict__ usr_emb,    // [NUM_USER,64]
    const float* __restrict__ ent_emb,    // [NUM_ENT,64]
    const float* __restrict__ rel_emb,    // [32,64]
    const float* __restrict__ conv_w,     // [1,8,3,3] OIHW
    const float* __restrict__ conv_b,     // [1]
    const float* __restrict__ agg_w,      // [64,64] row-major (d,j)
    const float* __restrict__ agg_b,      // [64]
    float*       __restrict__ out,        // [B]
    int B)
{
    __shared__ float s_aggw[64 * 64];   // 16 KB
    __shared__ float s_h[4][64];

    const int tid  = threadIdx.x;
    const int lane = tid & 63;
    const int wave = tid >> 6;

    // Stage agg_w into LDS once per block (broadcast-reused 4x64 times).
    for (int i = tid; i < 64 * 64; i += 256) s_aggw[i] = agg_w[i];
    __syncthreads();

    const int b      = blockIdx.x * 4 + wave;
    const bool live  = (b < B);
    const int bb     = live ? b : (B - 1);   // clamp so barriers stay uniform

    // ---------------- user side ----------------
    const int   ub  = u[bb];
    const float usr = usr_emb[ub * 64 + lane];

    float ue[8];
#pragma unroll
    for (int c = 0; c < 8; ++c) {
        const int e = uai[bb * 8 + c];
        ue[c] = usr * ent_emb[e * 64 + lane];
    }

    // conv2d NCHW with H=D=64, W=1, pad 1: only kw=1 column of the 3x3 filter
    // contributes. y[d] = conv_b + sum_c ( w[c,0,1]*ue[c][d-1]
    //                                    + w[c,1,1]*ue[c][d]
    //                                    + w[c,2,1]*ue[c][d+1] )
    float user_e = conv_b[0];
#pragma unroll
    for (int c = 0; c < 8; ++c) {
        const float w0 = conv_w[c * 9 + 1];  // kh=0, kw=1
        const float w1 = conv_w[c * 9 + 4];  // kh=1, kw=1
        const float w2 = conv_w[c * 9 + 7];  // kh=2, kw=1
        float prev = __shfl_up(ue[c], 1, 64);
        float next = __shfl_down(ue[c], 1, 64);
        if (lane == 0)  prev = 0.0f;
        if (lane == 63) next = 0.0f;
        user_e = fmaf(w0, prev, user_e);
        user_e = fmaf(w1, ue[c], user_e);
        user_e = fmaf(w2, next, user_e);
    }

    // ---------------- item side ----------------
    const int vb = v[bb];

    // scores[k] = sum_d user_e[d] * rel_emb[rel_idx[k]][d]  (full-wave reduce)
    float sc[8];
#pragma unroll
    for (int k = 0; k < 8; ++k) {
        const int r = adj_rel[vb * 8 + k];
        float p = user_e * rel_emb[r * 64 + lane];
#pragma unroll
        for (int off = 32; off >= 1; off >>= 1)
            p += __shfl_xor(p, off, 64);
        sc[k] = p;   // every lane now holds the full sum
    }

    // softmax over the 8 scores (redundantly per lane; values are wave-uniform)
    float m = sc[0];
#pragma unroll
    for (int k = 1; k < 8; ++k) m = fmaxf(m, sc[k]);
    float ek[8];
    float denom = 0.0f;
#pragma unroll
    for (int k = 0; k < 8; ++k) { ek[k] = __expf(sc[k] - m); denom += ek[k]; }
    const float inv_denom = 1.0f / denom;

    // h = self_vec + sum_k attn[k] * neigh[k]
    float h = ent_emb[vb * 64 + lane];
#pragma unroll
    for (int k = 0; k < 8; ++k) {
        const int n = adj_ent[vb * 8 + k];
        h = fmaf(ek[k] * inv_denom, ent_emb[n * 64 + lane], h);
    }

    // item = sigmoid(h @ agg_w + agg_b): lane = output column j
    s_h[wave][lane] = h;
    __syncthreads();

    float acc = agg_b[lane];
#pragma unroll 16
    for (int d = 0; d < 64; ++d)
        acc = fmaf(s_h[wave][d], s_aggw[d * 64 + lane], acc);
    const float item = 1.0f / (1.0f + __expf(-acc));

    // out[b] = sigmoid(sum_d user_e[d] * item[d])
    float p = user_e * item;
#pragma unroll
    for (int off = 32; off >= 1; off >>= 1)
        p += __shfl_xor(p, off, 64);

    if (live && lane == 0)
        out[b] = 1.0f / (1.0f + __expf(-p));
}

extern "C" void kernel_launch(void* const* d_in, const int* in_sizes, int n_in,
                              void* d_out, int out_size, void* d_ws, size_t ws_size,
                              hipStream_t stream) {
    const int*   u        = (const int*)  d_in[0];
    const int*   v        = (const int*)  d_in[1];
    const int*   uai      = (const int*)  d_in[2];
    const int*   adj_ent  = (const int*)  d_in[3];
    const int*   adj_rel  = (const int*)  d_in[4];
    const float* usr_emb  = (const float*)d_in[5];
    const float* ent_emb  = (const float*)d_in[6];
    const float* rel_emb  = (const float*)d_in[7];
    const float* conv_w   = (const float*)d_in[8];
    const float* conv_b   = (const float*)d_in[9];
    const float* agg_w    = (const float*)d_in[10];
    const float* agg_b    = (const float*)d_in[11];
    float*       out      = (float*)d_out;

    const int B = in_sizes[0];
    const int grid = (B + 3) / 4;   // 4 waves (batch elems) per 256-thread block
    pifsa_gnn_kernel<<<grid, 256, 0, stream>>>(
        u, v, uai, adj_ent, adj_rel, usr_emb, ent_emb, rel_emb,
        conv_w, conv_b, agg_w, agg_b, out, B);
}

// Round 2
// 357.701 us; speedup vs baseline: 1.0121x; 1.0121x over previous
//
#include <hip/hip_runtime.h>
#include <math.h>

// Lane layout: l = 16*g + q, g = group (0..3), q = quarter (0..15).
// Every per-b length-64 vector (usr, user_e, h, item) lives as float4 per lane,
// covering d = 4q..4q+3, replicated identically across the 4 groups.
// Row gathers: group g fetches row-slot g => one f4 load = 4 rows (1 KB).
// One wave per batch element. No LDS, no barriers.

__device__ __forceinline__ float4 ld4(const float* p) {
    return *reinterpret_cast<const float4*>(p);
}
__device__ __forceinline__ float dot4(float4 a, float4 b) {
    return fmaf(a.x, b.x, fmaf(a.y, b.y, fmaf(a.z, b.z, a.w * b.w)));
}
__device__ __forceinline__ float4 fma4(float s, float4 a, float4 acc) {
    acc.x = fmaf(s, a.x, acc.x);
    acc.y = fmaf(s, a.y, acc.y);
    acc.z = fmaf(s, a.z, acc.z);
    acc.w = fmaf(s, a.w, acc.w);
    return acc;
}
__device__ __forceinline__ float4 xgroup_sum4(float4 v) {  // sum over the 4 groups
    v.x += __shfl_xor(v.x, 16, 64); v.x += __shfl_xor(v.x, 32, 64);
    v.y += __shfl_xor(v.y, 16, 64); v.y += __shfl_xor(v.y, 32, 64);
    v.z += __shfl_xor(v.z, 16, 64); v.z += __shfl_xor(v.z, 32, 64);
    v.w += __shfl_xor(v.w, 16, 64); v.w += __shfl_xor(v.w, 32, 64);
    return v;
}
__device__ __forceinline__ float4 shfl4(float4 v, int src) {
    float4 r;
    r.x = __shfl(v.x, src, 64);
    r.y = __shfl(v.y, src, 64);
    r.z = __shfl(v.z, src, 64);
    r.w = __shfl(v.w, src, 64);
    return r;
}

__global__ __launch_bounds__(256) void pifsa_gnn_kernel(
    const int*   __restrict__ u,          // [B]
    const int*   __restrict__ v,          // [B]
    const int*   __restrict__ uai,        // [B,8]
    const int*   __restrict__ adj_ent,    // [NUM_ENT,8]
    const int*   __restrict__ adj_rel,    // [NUM_ENT,8]
    const float* __restrict__ usr_emb,    // [NUM_USER,64]
    const float* __restrict__ ent_emb,    // [NUM_ENT,64]
    const float* __restrict__ rel_emb,    // [32,64]
    const float* __restrict__ conv_w,     // [1,8,3,3] OIHW
    const float* __restrict__ conv_b,     // [1]
    const float* __restrict__ agg_w,      // [64,64] (d,j) row-major
    const float* __restrict__ agg_b,      // [64]
    float*       __restrict__ out,        // [B]
    int B)
{
    const int gtid = blockIdx.x * 256 + threadIdx.x;
    const int b    = gtid >> 6;
    if (b >= B) return;

    const int l  = threadIdx.x & 63;
    const int g  = l >> 4;
    const int q  = l & 15;
    const int d0 = q << 2;          // first of this lane's 4 dims

    // ---- indices (per-lane loads; uniform within a 16-lane group) ----
    const int ub = u[b];
    const int vb = v[b];
    const int c0 = g, c1 = g + 4;   // this group's two channel/neighbor slots
    const int e0 = uai[b * 8 + c0];
    const int e1 = uai[b * 8 + c1];
    const int r0 = adj_rel[vb * 8 + c0];
    const int r1 = adj_rel[vb * 8 + c1];
    const int n0 = adj_ent[vb * 8 + c0];
    const int n1 = adj_ent[vb * 8 + c1];

    // ---- user side: ue[c] = usr * ent_emb[uai[c]] ----
    const float4 usr = ld4(usr_emb + ub * 64 + d0);
    float4 a0 = ld4(ent_emb + (size_t)e0 * 64 + d0);
    float4 a1 = ld4(ent_emb + (size_t)e1 * 64 + d0);
    float4 ue0, ue1;
    ue0.x = usr.x * a0.x; ue0.y = usr.y * a0.y; ue0.z = usr.z * a0.z; ue0.w = usr.w * a0.w;
    ue1.x = usr.x * a1.x; ue1.y = usr.y * a1.y; ue1.z = usr.z * a1.z; ue1.w = usr.w * a1.w;

    // ---- conv along d (W=1 => only the kw=1 column of each 3x3 filter) ----
    const float w0a = conv_w[c0 * 9 + 1], w1a = conv_w[c0 * 9 + 4], w2a = conv_w[c0 * 9 + 7];
    const float w0b = conv_w[c1 * 9 + 1], w1b = conv_w[c1 * 9 + 4], w2b = conv_w[c1 * 9 + 7];

    float4 cacc = make_float4(0.f, 0.f, 0.f, 0.f);
    {
        float pw = __shfl(ue0.w, (l - 1) & 63, 64); if (q == 0)  pw = 0.f;
        float nx = __shfl(ue0.x, (l + 1) & 63, 64); if (q == 15) nx = 0.f;
        float4 prev = make_float4(pw, ue0.x, ue0.y, ue0.z);
        float4 next = make_float4(ue0.y, ue0.z, ue0.w, nx);
        cacc = fma4(w1a, ue0, cacc);
        cacc = fma4(w0a, prev, cacc);
        cacc = fma4(w2a, next, cacc);
    }
    {
        float pw = __shfl(ue1.w, (l - 1) & 63, 64); if (q == 0)  pw = 0.f;
        float nx = __shfl(ue1.x, (l + 1) & 63, 64); if (q == 15) nx = 0.f;
        float4 prev = make_float4(pw, ue1.x, ue1.y, ue1.z);
        float4 next = make_float4(ue1.y, ue1.z, ue1.w, nx);
        cacc = fma4(w1b, ue1, cacc);
        cacc = fma4(w0b, prev, cacc);
        cacc = fma4(w2b, next, cacc);
    }
    cacc = xgroup_sum4(cacc);      // sum the 8 channels (2 per group)
    const float cb = conv_b[0];
    float4 user_e = make_float4(cacc.x + cb, cacc.y + cb, cacc.z + cb, cacc.w + cb);

    // ---- scores: sc[k] = user_e . rel_emb[rel_idx[k]]  (k = g and g+4) ----
    float p0 = dot4(user_e, ld4(rel_emb + r0 * 64 + d0));
    float p1 = dot4(user_e, ld4(rel_emb + r1 * 64 + d0));
#pragma unroll
    for (int off = 1; off <= 8; off <<= 1) {
        p0 += __shfl_xor(p0, off, 64);
        p1 += __shfl_xor(p1, off, 64);
    }
    // collect all 8 scores into every lane
    float s[8];
#pragma unroll
    for (int kk = 0; kk < 4; ++kk) {
        s[kk]     = __shfl(p0, kk * 16, 64);
        s[kk + 4] = __shfl(p1, kk * 16, 64);
    }

    // ---- softmax over 8 (redundant per lane) ----
    float m = s[0];
#pragma unroll
    for (int k = 1; k < 8; ++k) m = fmaxf(m, s[k]);
    float den = 0.f;
    float ek[8];
#pragma unroll
    for (int k = 0; k < 8; ++k) { ek[k] = __expf(s[k] - m); den += ek[k]; }
    const float inv_den = 1.f / den;
    const float at0 = ek[c0] * inv_den;   // this group's two attention weights
    const float at1 = ek[c1] * inv_den;

    // ---- h = self + sum_k attn[k] * neigh[k] ----
    float4 nb0 = ld4(ent_emb + (size_t)n0 * 64 + d0);
    float4 nb1 = ld4(ent_emb + (size_t)n1 * 64 + d0);
    float4 hp = make_float4(0.f, 0.f, 0.f, 0.f);
    hp = fma4(at0, nb0, hp);
    hp = fma4(at1, nb1, hp);
    hp = xgroup_sum4(hp);
    const float4 self4 = ld4(ent_emb + (size_t)vb * 64 + d0);
    float4 h4 = make_float4(self4.x + hp.x, self4.y + hp.y, self4.z + hp.z, self4.w + hp.w);

    // ---- item = sigmoid(h @ agg_w + agg_b) ----
    // lane (g,q): accumulates output cols j = 4q..4q+3 over d in [16g, 16g+16).
    // agg_w is 16 KB => L1-hot; each f4 load instruction pulls 4 rows (1 KB).
    float4 acc = make_float4(0.f, 0.f, 0.f, 0.f);
#pragma unroll
    for (int i = 0; i < 4; ++i) {
        const float4 hb = shfl4(h4, 20 * g + i);       // h[16g+4i .. 16g+4i+3]
        const float* wrow = agg_w + (16 * g + 4 * i) * 64 + d0;
        acc = fma4(hb.x, ld4(wrow),       acc);
        acc = fma4(hb.y, ld4(wrow + 64),  acc);
        acc = fma4(hb.z, ld4(wrow + 128), acc);
        acc = fma4(hb.w, ld4(wrow + 192), acc);
    }
    acc = xgroup_sum4(acc);                            // sum d-quarters
    const float4 bias = ld4(agg_b + d0);
    float4 item;
    item.x = 1.f / (1.f + __expf(-(acc.x + bias.x)));
    item.y = 1.f / (1.f + __expf(-(acc.y + bias.y)));
    item.z = 1.f / (1.f + __expf(-(acc.z + bias.z)));
    item.w = 1.f / (1.f + __expf(-(acc.w + bias.w)));

    // ---- out[b] = sigmoid(user_e . item) ----
    float p = dot4(user_e, item);
#pragma unroll
    for (int off = 1; off <= 8; off <<= 1)
        p += __shfl_xor(p, off, 64);

    if (l == 0)
        out[b] = 1.f / (1.f + __expf(-p));
}

extern "C" void kernel_launch(void* const* d_in, const int* in_sizes, int n_in,
                              void* d_out, int out_size, void* d_ws, size_t ws_size,
                              hipStream_t stream) {
    const int*   u        = (const int*)  d_in[0];
    const int*   v        = (const int*)  d_in[1];
    const int*   uai      = (const int*)  d_in[2];
    const int*   adj_ent  = (const int*)  d_in[3];
    const int*   adj_rel  = (const int*)  d_in[4];
    const float* usr_emb  = (const float*)d_in[5];
    const float* ent_emb  = (const float*)d_in[6];
    const float* rel_emb  = (const float*)d_in[7];
    const float* conv_w   = (const float*)d_in[8];
    const float* conv_b   = (const float*)d_in[9];
    const float* agg_w    = (const float*)d_in[10];
    const float* agg_b    = (const float*)d_in[11];
    float*       out      = (float*)d_out;

    const int B = in_sizes[0];
    const int grid = (B + 3) / 4;   // one wave per b, 4 waves per 256-thread block
    pifsa_gnn_kernel<<<grid, 256, 0, stream>>>(
        u, v, uai, adj_ent, adj_rel, usr_emb, ent_emb, rel_emb,
        conv_w, conv_b, agg_w, agg_b, out, B);
}